// Round 6
// baseline (432.006 us; speedup 1.0000x reference)
//
#include <hip/hip_runtime.h>
#include <math.h>

// B=4 S=1024 D=1024 P=128 H=8 E=16, NT=4096, TPOS=2047

typedef __attribute__((ext_vector_type(8))) short short8;
typedef __attribute__((ext_vector_type(4))) float floatx4;

__device__ __forceinline__ float bf2f(unsigned int u) {
    union { unsigned int i; float f; } x; x.i = (u & 0xffffu) << 16; return x.f;
}
__device__ __forceinline__ unsigned short f2bf(float f) {
    union { float f; unsigned int i; } x; x.f = f;
    unsigned int r = x.i + 0x7fffu + ((x.i >> 16) & 1u);
    return (unsigned short)(r >> 16);
}

// async global->LDS: per-lane global addr, wave-uniform LDS base; lane data at base + lane*16
__device__ __forceinline__ void gload16(const void* g, void* l) {
    __builtin_amdgcn_global_load_lds(
        (const __attribute__((address_space(1))) unsigned int*)(uintptr_t)g,
        (__attribute__((address_space(3))) unsigned int*)(uintptr_t)l,
        16, 0, 0);
}

// Fragment layouts (16x16x32 bf16 MFMA), HW-verified R2-R5:
//   A-frag (MxK):  afrag[m>>4][k>>5][((k&31)>>3)*16 + (m&15)][k&7]
//   B-frag (KxN):  bfrag[n>>4][k>>5][((k&31)>>3)*16 + (n&15)][k&7]
//   C/D:           col = lane&15, row = (lane>>4)*4 + reg

// ---------------- Kernel 1: selection + top-8 + sigmoid + curr->A-frag (fused) ----------------
__global__ __launch_bounds__(256) void k_sel(const float* __restrict__ curr,
                                             const float* __restrict__ sel_dst,
                                             float* __restrict__ selval,
                                             int* __restrict__ selidx,
                                             unsigned short* __restrict__ afrag) {
    __shared__ float row[1024];
    __shared__ float sel[16];
    const int token = blockIdx.x;
    const int t = threadIdx.x;
    const float4 v = ((const float4*)(curr + (size_t)token * 1024))[t];
    ((float4*)row)[t] = v;
    // fused conv: curr row -> A-frag bf16 (mapping from R3's k_conv_act, m=token)
    {
        const int mt = token >> 4, kc = t >> 3;
        const int lane = ((t & 7) >> 1) * 16 + (token & 15);
        const size_t off = (((size_t)mt * 32 + kc) * 64 + lane) * 8 + 4 * (t & 1);
        uint2 o;
        o.x = (unsigned)f2bf(v.x) | ((unsigned)f2bf(v.y) << 16);
        o.y = (unsigned)f2bf(v.z) | ((unsigned)f2bf(v.w) << 16);
        *(uint2*)(afrag + off) = o;
    }
    __syncthreads();
    const int wv = t >> 6, lane = t & 63;
    for (int e0 = 0; e0 < 4; ++e0) {
        const int e = wv * 4 + e0;
        const float* w = sel_dst + e * 1024;
        float p = 0.f;
        for (int i = lane; i < 1024; i += 64) p += row[i] * w[i];
        for (int off = 32; off; off >>= 1) p += __shfl_down(p, off, 64);
        if (lane == 0) sel[e] = p;
    }
    __syncthreads();
    if (t == 0) {
        float v16[16];
#pragma unroll
        for (int e = 0; e < 16; ++e) v16[e] = sel[e];
#pragma unroll
        for (int r = 0; r < 8; ++r) {
            int bi = 0; float bv = v16[0];
#pragma unroll
            for (int e = 1; e < 16; ++e) { if (v16[e] > bv) { bv = v16[e]; bi = e; } }
            selidx[token * 8 + r] = bi;
            selval[token * 8 + r] = 1.f / (1.f + __expf(-bv));
            v16[bi] = -INFINITY;
        }
    }
}

// ---------------- Kernel: activation f32 row-major (4096x1024) -> A-frag bf16 (attend) ----------------
__global__ __launch_bounds__(256) void k_conv_act(const float* __restrict__ src,
                                                  unsigned short* __restrict__ dst) {
    const int m = blockIdx.x;
    const int t = threadIdx.x;
    const float4 v = *(const float4*)(src + (size_t)m * 1024 + 4 * t);
    const int mt = m >> 4, kc = t >> 3;
    const int lane = ((t & 7) >> 1) * 16 + (m & 15);
    const size_t off = (((size_t)mt * 32 + kc) * 64 + lane) * 8 + 4 * (t & 1);
    uint2 o;
    o.x = (unsigned)f2bf(v.x) | ((unsigned)f2bf(v.y) << 16);
    o.y = (unsigned)f2bf(v.z) | ((unsigned)f2bf(v.w) << 16);
    *(uint2*)(dst + off) = o;
}

// ---------------- Merged: weights->B-frag (bx<4352) + kpos->B-frag (bx>=4352) ----------------
__global__ __launch_bounds__(256) void k_misc(const float* __restrict__ w_q,
                                              const float* __restrict__ w_out,
                                              const float* __restrict__ w_kv,
                                              const float* __restrict__ pos_pk,
                                              const float* __restrict__ scale,
                                              unsigned short* __restrict__ bfragq,
                                              unsigned short* __restrict__ bfragw,
                                              unsigned short* __restrict__ bfragkv,
                                              unsigned short* __restrict__ kposfg) {
    const int bx = blockIdx.x;
    const int t = threadIdx.x;
    if (bx < 4352) {
        float v[4];
        if (bx < 2048) {
            // w_q: B[k=i][n=e*128+p], K=1024 (KC=32), N=2048
            const unsigned u = bx * 256 + t;
            const int p = u & 127, e = (u >> 7) & 15, kk = u >> 11;
#pragma unroll
            for (int d = 0; d < 4; ++d) v[d] = w_q[(size_t)e * 131072 + (size_t)(4 * kk + d) * 128 + p];
            const int n = e * 128 + p;
            const int nt = n >> 4, kc = kk >> 3;
            const int lane = ((kk & 7) >> 1) * 16 + (n & 15);
            const size_t off = (((size_t)nt * 32 + kc) * 64 + lane) * 8 + 4 * (kk & 1);
            uint2 o;
            o.x = (unsigned)f2bf(v[0]) | ((unsigned)f2bf(v[1]) << 16);
            o.y = (unsigned)f2bf(v[2]) | ((unsigned)f2bf(v[3]) << 16);
            *(uint2*)(bfragq + off) = o;
        } else if (bx < 4096) {
            // w_out: row-major 2048x1024, K=2048 (KC=64), N=1024
            const unsigned u = (bx - 2048) * 256 + t;
            const int n = ((bx & 3) * 256 + t) & 1023;
            const int kk = u >> 10;
#pragma unroll
            for (int d = 0; d < 4; ++d) v[d] = w_out[(size_t)(4 * kk + d) * 1024 + n];
            const int nt = n >> 4, kc = kk >> 3;
            const int lane = ((kk & 7) >> 1) * 16 + (n & 15);
            const size_t off = (((size_t)nt * 64 + kc) * 64 + lane) * 8 + 4 * (kk & 1);
            uint2 o;
            o.x = (unsigned)f2bf(v[0]) | ((unsigned)f2bf(v[1]) << 16);
            o.y = (unsigned)f2bf(v[2]) | ((unsigned)f2bf(v[3]) << 16);
            *(uint2*)(bfragw + off) = o;
        } else {
            // w_kv: row-major 1024x256, K=1024 (KC=32), N=256
            const int n = t;
            const int kk = bx - 4096;
#pragma unroll
            for (int d = 0; d < 4; ++d) v[d] = w_kv[(size_t)(4 * kk + d) * 256 + n];
            const int nt = n >> 4, kc = kk >> 3;
            const int lane = ((kk & 7) >> 1) * 16 + (n & 15);
            const size_t off = (((size_t)nt * 32 + kc) * 64 + lane) * 8 + 4 * (kk & 1);
            uint2 o;
            o.x = (unsigned)f2bf(v[0]) | ((unsigned)f2bf(v[1]) << 16);
            o.y = (unsigned)f2bf(v[2]) | ((unsigned)f2bf(v[3]) << 16);
            *(uint2*)(bfragkv + off) = o;
        }
    } else {
        // kpos: 8 tp-rows per block, 256 threads (2 per p-column)
        __shared__ float pe[8][1024];  // 32 KB
        const int t0 = (bx - 4352) * 8;
        const float c1 = -logf(10000.f) / 1024.f;
        for (int rr = 0; rr < 8; ++rr) {
            int tp = t0 + rr; if (tp > 2046) tp = 2046;
            const float pos = (float)(tp - 1023);
            for (int i = t; i < 512; i += 256) {
                const float dv = expf((2.f * (float)i) * c1);
                const float ang = pos * dv;
                pe[rr][2 * i]     = sinf(ang);
                pe[rr][2 * i + 1] = cosf(ang);
            }
        }
        __syncthreads();
        const float sc = sqrtf(scale[0]);
        const int p = t & 127, rh = t >> 7;   // thread handles rows rh, rh+2, rh+4, rh+6
        float acc[4] = {0.f, 0.f, 0.f, 0.f};
        const float* wrow = pos_pk + (size_t)p * 1024;
        for (int d = 0; d < 1024; ++d) {
            const float wv = wrow[d];
#pragma unroll
            for (int i = 0; i < 4; ++i) acc[i] += pe[rh + 2 * i][d] * wv;
        }
        const int ch = p >> 5, pr = p & 31;
#pragma unroll
        for (int i = 0; i < 4; ++i) {
            const int tp = t0 + rh + 2 * i;
            if (tp >= 2048) continue;
            const float v = (tp <= 2046) ? acc[i] * sc : 0.f;
            const size_t addr = (((size_t)(tp >> 4) * 4 + ch) * 64 + (pr >> 3) * 16 + (tp & 15)) * 8 + (pr & 7);
            kposfg[addr] = f2bf(v);
        }
    }
}

// ---------------- MFMA GEMM core: 128x64 tile, 4 waves, frag-ordered global in ----------------
// wave w: row-subtiles [ (w>>1)*4 .. +3 ] x col-subtiles [ (w&1)*2 .. +1 ]
__device__ __forceinline__ void gemm_core64(const unsigned short* __restrict__ Afrag,
                                            const unsigned short* __restrict__ Bfrag,
                                            int mt0, int nt0, int KC,
                                            unsigned short (*aT)[512],
                                            unsigned short (*bT)[512],
                                            floatx4 acc[4][2]) {
    const int t = threadIdx.x;
    const int w = t >> 6, lane = t & 63;
    const int wm = w >> 1, wn = w & 1;
    for (int kc = 0; kc < KC; ++kc) {
        __syncthreads();
        {
            const int fi = w * 3;
#pragma unroll
            for (int l = 0; l < 3; ++l) {
                const int f = fi + l;   // 0..11: 8 A-frags then 4 B-frags
                if (f < 8)
                    gload16(Afrag + (((size_t)(mt0 + f) * KC + kc) * 64 + lane) * 8, &aT[f][0]);
                else
                    gload16(Bfrag + (((size_t)(nt0 + f - 8) * KC + kc) * 64 + lane) * 8, &bT[f - 8][0]);
            }
        }
        __syncthreads();
        short8 af[4], bf[2];
#pragma unroll
        for (int i = 0; i < 4; ++i) af[i] = *(const short8*)&aT[wm * 4 + i][lane * 8];
#pragma unroll
        for (int j = 0; j < 2; ++j) bf[j] = *(const short8*)&bT[wn * 2 + j][lane * 8];
#pragma unroll
        for (int i = 0; i < 4; ++i)
#pragma unroll
            for (int j = 0; j < 2; ++j)
                acc[i][j] = __builtin_amdgcn_mfma_f32_16x16x32_bf16(af[i], bf[j], acc[i][j], 0, 0, 0);
    }
}

// ---------------- GEMM: qall = curr @ [w_q] * sc -> bf16 row-major 4096x2048 ----------------
__global__ __launch_bounds__(256) void k_gemm_qall(const unsigned short* __restrict__ Afrag,
                                                   const unsigned short* __restrict__ Bfrag,
                                                   const float* __restrict__ scale,
                                                   unsigned short* __restrict__ qall) {
    __shared__ __align__(16) unsigned short aT[8][512], bT[4][512];
    floatx4 acc[4][2];
#pragma unroll
    for (int i = 0; i < 4; ++i) { acc[i][0] = (floatx4){0,0,0,0}; acc[i][1] = (floatx4){0,0,0,0}; }
    gemm_core64(Afrag, Bfrag, blockIdx.x * 8, blockIdx.y * 4, 32, aT, bT, acc);
    const float sc = sqrtf(scale[0]);
    const int t = threadIdx.x, w = t >> 6, lane = t & 63;
    const int wm = w >> 1, wn = w & 1, lq = lane >> 4, lm = lane & 15;
#pragma unroll
    for (int i = 0; i < 4; ++i)
#pragma unroll
        for (int j = 0; j < 2; ++j)
#pragma unroll
            for (int r = 0; r < 4; ++r)
                qall[(size_t)(blockIdx.x * 128 + (wm * 4 + i) * 16 + lq * 4 + r) * 2048 +
                     blockIdx.y * 64 + (wn * 2 + j) * 16 + lm] = f2bf(acc[i][j][r] * sc);
}

// ---------------- GEMM: out = zfrag @ w_out -> f32 row-major 4096x1024 ----------------
__global__ __launch_bounds__(256) void k_gemm_out(const unsigned short* __restrict__ Afrag,
                                                  const unsigned short* __restrict__ Bfrag,
                                                  float* __restrict__ out) {
    __shared__ __align__(16) unsigned short aT[8][512], bT[4][512];
    floatx4 acc[4][2];
#pragma unroll
    for (int i = 0; i < 4; ++i) { acc[i][0] = (floatx4){0,0,0,0}; acc[i][1] = (floatx4){0,0,0,0}; }
    gemm_core64(Afrag, Bfrag, blockIdx.x * 8, blockIdx.y * 4, 64, aT, bT, acc);
    const int t = threadIdx.x, w = t >> 6, lane = t & 63;
    const int wm = w >> 1, wn = w & 1, lq = lane >> 4, lm = lane & 15;
#pragma unroll
    for (int i = 0; i < 4; ++i)
#pragma unroll
        for (int j = 0; j < 2; ++j)
#pragma unroll
            for (int r = 0; r < 4; ++r)
                out[(size_t)(blockIdx.x * 128 + (wm * 4 + i) * 16 + lq * 4 + r) * 1024 +
                    blockIdx.y * 64 + (wn * 2 + j) * 16 + lm] = acc[i][j][r];
}

// ---------------- GEMM: kv = attend @ w_kv -> K/V B-fragment layouts (bf16) ----------------
__global__ __launch_bounds__(256) void k_gemm_kv(const unsigned short* __restrict__ Afrag,
                                                 const unsigned short* __restrict__ Bfrag,
                                                 const float* __restrict__ scale,
                                                 unsigned short* __restrict__ kfragg,
                                                 unsigned short* __restrict__ vfragg) {
    __shared__ __align__(16) unsigned short aT[8][512], bT[4][512];
    floatx4 acc[4][2];
#pragma unroll
    for (int i = 0; i < 4; ++i) { acc[i][0] = (floatx4){0,0,0,0}; acc[i][1] = (floatx4){0,0,0,0}; }
    gemm_core64(Afrag, Bfrag, blockIdx.x * 8, blockIdx.y * 4, 32, aT, bT, acc);
    const float sc = sqrtf(scale[0]);
    const int t = threadIdx.x, w = t >> 6, lane = t & 63;
    const int wm = w >> 1, wn = w & 1, lq = lane >> 4, lm = lane & 15;
#pragma unroll
    for (int i = 0; i < 4; ++i)
#pragma unroll
        for (int j = 0; j < 2; ++j) {
            const int n = blockIdx.y * 64 + (wn * 2 + j) * 16 + lm;
#pragma unroll
            for (int r = 0; r < 4; ++r) {
                const int tok = blockIdx.x * 128 + (wm * 4 + i) * 16 + lq * 4 + r;
                const int bb = tok >> 10, jj = tok & 1023;
                if (n < 128) {
                    const int p = n;
                    const size_t addr = ((((size_t)bb * 64 + (jj >> 4)) * 4 + (p >> 5)) * 64 +
                                         ((p & 31) >> 3) * 16 + (jj & 15)) * 8 + (p & 7);
                    kfragg[addr] = f2bf(acc[i][j][r] * sc);
                } else {
                    const int p = n - 128;
                    const size_t addr = ((((size_t)bb * 32 + (jj >> 5)) * 8 + (p >> 4)) * 64 +
                                         ((jj & 31) >> 3) * 16 + (p & 15)) * 8 + (jj & 7);
                    vfragg[addr] = f2bf(acc[i][j][r]);
                }
            }
        }
}

// ---------------- k_attn R6: head-shared blocks (4 waves = 4 heads, same 16 s-rows),
//                  rolling kpos window (2 new subtiles/iter), fixed-max softmax ----------------
#define ATTN_FM 8.0f

__device__ __forceinline__ void attn_step6(const char*& pk, const char*& pv, const char*& pp,
                                           short8 (&kf)[8], short8 (&kfN)[8],
                                           const short8 (&cry)[4], short8 (&n1)[4], short8 (&n2)[4],
                                           const short8 (&qf)[4], const short8& onesf,
                                           floatx4 (&acc)[8], floatx4& accl,
                                           unsigned short* __restrict__ pl,
                                           const int loff,
                                           const int (&baddr)[4], const int (&bsel)[4],
                                           const int lq, const int lm) {
    // loads up front: 2 new kpos subtiles, V, next-iter K (prefetch)
#pragma unroll
    for (int c = 0; c < 4; ++c) {
        n1[c] = *(const short8*)(pp + 4096 + c * 1024 + loff);
        n2[c] = *(const short8*)(pp + 8192 + c * 1024 + loff);
    }
    short8 vf[8];
#pragma unroll
    for (int nt = 0; nt < 8; ++nt)
        vf[nt] = *(const short8*)(pv + nt * 1024 + loff);
#pragma unroll
    for (int q = 0; q < 8; ++q)
        kfN[q] = *(const short8*)(pk + 8192 + q * 1024 + loff);

    // S_k = Q @ K^T (two 16x16 j-subtiles)
    floatx4 sk0 = {0.f, 0.f, 0.f, 0.f}, sk1 = {0.f, 0.f, 0.f, 0.f};
#pragma unroll
    for (int c = 0; c < 4; ++c) {
        sk0 = __builtin_amdgcn_mfma_f32_16x16x32_bf16(qf[c], kf[c], sk0, 0, 0, 0);
        sk1 = __builtin_amdgcn_mfma_f32_16x16x32_bf16(qf[c], kf[4 + c], sk1, 0, 0, 0);
    }
    // band: 3 diagonal subtiles (carried, new1, new2)
    floatx4 sp0 = {0.f, 0.f, 0.f, 0.f}, sp1 = {0.f, 0.f, 0.f, 0.f}, sp2 = {0.f, 0.f, 0.f, 0.f};
#pragma unroll
    for (int c = 0; c < 4; ++c) {
        sp0 = __builtin_amdgcn_mfma_f32_16x16x32_bf16(qf[c], cry[c], sp0, 0, 0, 0);
        sp1 = __builtin_amdgcn_mfma_f32_16x16x32_bf16(qf[c], n1[c], sp1, 0, 0, 0);
        sp2 = __builtin_amdgcn_mfma_f32_16x16x32_bf16(qf[c], n2[c], sp2, 0, 0, 0);
    }
    // diagonal gather via bpermute + fixed-max softmax
#pragma unroll
    for (int r = 0; r < 4; ++r) {
        const int a = baddr[r];
        const float b0 = __int_as_float(__builtin_amdgcn_ds_bpermute(a, __float_as_int(sp0[r])));
        const float b1 = __int_as_float(__builtin_amdgcn_ds_bpermute(a, __float_as_int(sp1[r])));
        const float b2 = __int_as_float(__builtin_amdgcn_ds_bpermute(a, __float_as_int(sp2[r])));
        const float v0 = sk0[r] + (bsel[r] ? b0 : b1);
        const float v1 = sk1[r] + (bsel[r] ? b1 : b2);
        pl[(lq * 4 + r) * 56 + lm]      = f2bf(__expf(v0 - ATTN_FM));
        pl[(lq * 4 + r) * 56 + 16 + lm] = f2bf(__expf(v1 - ATTN_FM));
    }
    asm volatile("" ::: "memory");   // per-wave LDS RAW ordering
    const short8 pf = *(const short8*)(pl + lm * 56 + lq * 8);
#pragma unroll
    for (int nt = 0; nt < 8; ++nt)
        acc[nt] = __builtin_amdgcn_mfma_f32_16x16x32_bf16(pf, vf[nt], acc[nt], 0, 0, 0);
    accl = __builtin_amdgcn_mfma_f32_16x16x32_bf16(pf, onesf, accl, 0, 0, 0);
    pk += 8192; pv += 8192; pp += 8192;
}

__global__ __launch_bounds__(256, 2) void k_attn(const unsigned short* __restrict__ qall,
                                                 const unsigned short* __restrict__ kfragg,
                                                 const unsigned short* __restrict__ vfragg,
                                                 const unsigned short* __restrict__ kposfg,
                                                 const int* __restrict__ selidx,
                                                 const float* __restrict__ selval,
                                                 unsigned short* __restrict__ zfrag) {
    __shared__ __align__(16) unsigned short plds[2][4][16][56];  // 14 KB, parity x wave

    const int t = threadIdx.x;
    const int w = t >> 6, lane = t & 63;
    const int st = blockIdx.x & 63;            // 64 s-tiles of 16 rows
    const int hg = (blockIdx.x >> 6) & 1;      // head group
    const int b = blockIdx.x >> 7;
    const int h = hg * 4 + w;                  // wave = head
    const int s0 = st * 16;
    const int lq = lane >> 4;
    const int lm = lane & 15;
    const int loff = lane * 16;

    // Q A-fragments (rows = tokens s0..s0+15, head h's selected expert per token)
    short8 qf[4];
    {
        const int token = b * 1024 + s0 + lm;
        const int e = selidx[token * 8 + h];
        const unsigned short* qb = qall + (size_t)token * 2048 + e * 128 + lq * 8;
#pragma unroll
        for (int c = 0; c < 4; ++c) qf[c] = *(const short8*)(qb + c * 32);
    }
    short8 onesf;
#pragma unroll
    for (int i = 0; i < 8; ++i) onesf[i] = (short)0x3F80;

    // bpermute gather constants: c0 = 15 + lm - row, row = lq*4+r
    int baddr[4], bsel[4];
#pragma unroll
    for (int r = 0; r < 4; ++r) {
        const int c0 = 15 + lm - (lq * 4 + r);
        baddr[r] = (lq * 16 + (c0 & 15)) * 4;
        bsel[r] = (c0 < 16) ? 1 : 0;
    }

    floatx4 acc[8], accl;
#pragma unroll
    for (int nt = 0; nt < 8; ++nt) acc[nt] = (floatx4){0.f, 0.f, 0.f, 0.f};
    accl = (floatx4){0.f, 0.f, 0.f, 0.f};

    // streams: +8192 B per iteration; kpos window base depends only on s0 (shared by all 4 waves)
    const char* pk = (const char*)kfragg + (size_t)b * 262144;
    const char* pv = (const char*)vfragg + (size_t)b * 262144;
    const char* pp = (const char*)kposfg + (size_t)((1008 - s0) >> 4) * 4096;

    short8 kfA[8], kfB[8];
#pragma unroll
    for (int q = 0; q < 8; ++q)
        kfA[q] = *(const short8*)(pk + q * 1024 + loff);
    short8 cry[4], n1a[4], n2a[4], n1b[4], n2b[4];
#pragma unroll
    for (int c = 0; c < 4; ++c)
        cry[c] = *(const short8*)(pp + c * 1024 + loff);   // subtile G(0)

    unsigned short* pl0 = &plds[0][w][0][0];
    unsigned short* pl1 = &plds[1][w][0][0];
    for (int it2 = 0; it2 < 16; ++it2) {
        attn_step6(pk, pv, pp, kfA, kfB, cry, n1a, n2a, qf, onesf, acc, accl, pl0, loff, baddr, bsel, lq, lm);
        attn_step6(pk, pv, pp, kfB, kfA, n2a, n1b, n2b, qf, onesf, acc, accl, pl1, loff, baddr, bsel, lq, lm);
#pragma unroll
        for (int c = 0; c < 4; ++c) cry[c] = n2b[c];       // carry last subtile
    }
    // (final K prefetch reads 8 KB past batch K stream -> lands in vfragg, discarded)

    // epilogue: z -> A-fragment layout for out GEMM (KC=64); unselected slots zeroed by memset
#pragma unroll
    for (int r = 0; r < 4; ++r) {
        const int tok = b * 1024 + s0 + lq * 4 + r;
        const int e = selidx[tok * 8 + h];
        const float g = selval[tok * 8 + h] / accl[r];
        const int mt = tok >> 4, tm = tok & 15;
#pragma unroll
        for (int nt = 0; nt < 8; ++nt) {
            const int k = e * 128 + nt * 16 + lm;
            const int kc = k >> 5;
            const int lane2 = (((k & 31) >> 3) << 4) + tm;
            zfrag[(((size_t)mt * 64 + kc) * 64 + lane2) * 8 + (k & 7)] = f2bf(acc[nt][r] * g);
        }
    }
}

extern "C" void kernel_launch(void* const* d_in, const int* in_sizes, int n_in,
                              void* d_out, int out_size, void* d_ws, size_t ws_size,
                              hipStream_t stream) {
    const float* curr    = (const float*)d_in[0];  // (4,1024,1024)
    const float* attend  = (const float*)d_in[1];  // (4,1024,1024)
    const float* w_q     = (const float*)d_in[2];  // (16,1024,128)
    const float* w_kv    = (const float*)d_in[3];  // (1024,256)
    const float* w_out   = (const float*)d_in[4];  // (16,128,1024)
    const float* pos_pk  = (const float*)d_in[5];  // (128,1024)
    const float* sel_dst = (const float*)d_in[6];  // (16,1024)
    const float* scale   = (const float*)d_in[7];  // (1,)
    float* out = (float*)d_out;

    char* ws = (char*)d_ws;
    float* selval = (float*)ws;                                        // 128 KB
    int*   selidx = (int*)(ws + 131072);                               // 128 KB
    unsigned short* kposfg  = (unsigned short*)(ws + 262144);          // 512 KB
    unsigned short* kfragg  = (unsigned short*)(ws + 786432);          // 1 MB
    unsigned short* vfragg  = (unsigned short*)(ws + 1835008);         // 1 MB
    unsigned short* bfragq  = (unsigned short*)(ws + 2883584);         // 4 MB
    unsigned short* bfragw  = (unsigned short*)(ws + 7077888);         // 4 MB
    unsigned short* bfragkv = (unsigned short*)(ws + 11272192);        // 512 KB
    unsigned short* afrag   = (unsigned short*)(ws + 11796480);        // 8 MB (curr, then attend)
    unsigned short* qall    = (unsigned short*)(ws + 20185088);        // 16 MB
    unsigned short* zfrag   = (unsigned short*)(ws + 36962304);        // 16 MB
    // total ~51.3 MB

    k_misc<<<4608, 256, 0, stream>>>(w_q, w_out, w_kv, pos_pk, scale, bfragq, bfragw, bfragkv, kposfg);
    k_sel<<<4096, 256, 0, stream>>>(curr, sel_dst, selval, selidx, afrag);
    k_gemm_qall<<<dim3(32, 32), 256, 0, stream>>>(afrag, bfragq, scale, qall);
    k_conv_act<<<4096, 256, 0, stream>>>(attend, afrag);               // reuse afrag
    k_gemm_kv<<<dim3(32, 4), 256, 0, stream>>>(afrag, bfragkv, scale, kfragg, vfragg);
    hipMemsetAsync(zfrag, 0, (size_t)16777216, stream);
    k_attn<<<512, 256, 0, stream>>>(qall, kfragg, vfragg, kposfg, selidx, selval, zfrag);
    k_gemm_out<<<dim3(32, 16), 256, 0, stream>>>(zfrag, bfragw, out);
}

// Round 7
// 342.383 us; speedup vs baseline: 1.2618x; 1.2618x over previous
//
#include <hip/hip_runtime.h>
#include <math.h>

// B=4 S=1024 D=1024 P=128 H=8 E=16, NT=4096, TPOS=2047

typedef __attribute__((ext_vector_type(8))) short short8;
typedef __attribute__((ext_vector_type(4))) float floatx4;

__device__ __forceinline__ float bf2f(unsigned int u) {
    union { unsigned int i; float f; } x; x.i = (u & 0xffffu) << 16; return x.f;
}
__device__ __forceinline__ unsigned short f2bf(float f) {
    union { float f; unsigned int i; } x; x.f = f;
    unsigned int r = x.i + 0x7fffu + ((x.i >> 16) & 1u);
    return (unsigned short)(r >> 16);
}

// async global->LDS: per-lane global addr, wave-uniform LDS base; lane data at base + lane*16
__device__ __forceinline__ void gload16(const void* g, void* l) {
    __builtin_amdgcn_global_load_lds(
        (const __attribute__((address_space(1))) unsigned int*)(uintptr_t)g,
        (__attribute__((address_space(3))) unsigned int*)(uintptr_t)l,
        16, 0, 0);
}

// Fragment layouts (16x16x32 bf16 MFMA), HW-verified R2-R6:
//   A-frag (MxK):  afrag[m>>4][k>>5][((k&31)>>3)*16 + (m&15)][k&7]
//   B-frag (KxN):  bfrag[n>>4][k>>5][((k&31)>>3)*16 + (n&15)][k&7]
//   C/D:           col = lane&15, row = (lane>>4)*4 + reg

// ---------------- Kernel 1: selection + top-8 + sigmoid + curr->A-frag (fused) ----------------
__global__ __launch_bounds__(256) void k_sel(const float* __restrict__ curr,
                                             const float* __restrict__ sel_dst,
                                             float* __restrict__ selval,
                                             int* __restrict__ selidx,
                                             unsigned short* __restrict__ afrag) {
    __shared__ float row[1024];
    __shared__ float sel[16];
    const int token = blockIdx.x;
    const int t = threadIdx.x;
    const float4 v = ((const float4*)(curr + (size_t)token * 1024))[t];
    ((float4*)row)[t] = v;
    {
        const int mt = token >> 4, kc = t >> 3;
        const int lane = ((t & 7) >> 1) * 16 + (token & 15);
        const size_t off = (((size_t)mt * 32 + kc) * 64 + lane) * 8 + 4 * (t & 1);
        uint2 o;
        o.x = (unsigned)f2bf(v.x) | ((unsigned)f2bf(v.y) << 16);
        o.y = (unsigned)f2bf(v.z) | ((unsigned)f2bf(v.w) << 16);
        *(uint2*)(afrag + off) = o;
    }
    __syncthreads();
    const int wv = t >> 6, lane = t & 63;
    for (int e0 = 0; e0 < 4; ++e0) {
        const int e = wv * 4 + e0;
        const float* w = sel_dst + e * 1024;
        float p = 0.f;
        for (int i = lane; i < 1024; i += 64) p += row[i] * w[i];
        for (int off = 32; off; off >>= 1) p += __shfl_down(p, off, 64);
        if (lane == 0) sel[e] = p;
    }
    __syncthreads();
    if (t == 0) {
        float v16[16];
#pragma unroll
        for (int e = 0; e < 16; ++e) v16[e] = sel[e];
#pragma unroll
        for (int r = 0; r < 8; ++r) {
            int bi = 0; float bv = v16[0];
#pragma unroll
            for (int e = 1; e < 16; ++e) { if (v16[e] > bv) { bv = v16[e]; bi = e; } }
            selidx[token * 8 + r] = bi;
            selval[token * 8 + r] = 1.f / (1.f + __expf(-bv));
            v16[bi] = -INFINITY;
        }
    }
}

// ---------------- Kernel: activation f32 row-major (4096x1024) -> A-frag bf16 (attend) ----------------
__global__ __launch_bounds__(256) void k_conv_act(const float* __restrict__ src,
                                                  unsigned short* __restrict__ dst) {
    const int m = blockIdx.x;
    const int t = threadIdx.x;
    const float4 v = *(const float4*)(src + (size_t)m * 1024 + 4 * t);
    const int mt = m >> 4, kc = t >> 3;
    const int lane = ((t & 7) >> 1) * 16 + (m & 15);
    const size_t off = (((size_t)mt * 32 + kc) * 64 + lane) * 8 + 4 * (t & 1);
    uint2 o;
    o.x = (unsigned)f2bf(v.x) | ((unsigned)f2bf(v.y) << 16);
    o.y = (unsigned)f2bf(v.z) | ((unsigned)f2bf(v.w) << 16);
    *(uint2*)(dst + off) = o;
}

// ---------------- Kernel: weights f32 -> B-frag bf16 (w_q, w_out, w_kv, pos_pk) ----------------
__global__ __launch_bounds__(256) void k_conv_w(const float* __restrict__ w_q,
                                                const float* __restrict__ w_out,
                                                const float* __restrict__ w_kv,
                                                const float* __restrict__ pos_pk,
                                                unsigned short* __restrict__ bfragq,
                                                unsigned short* __restrict__ bfragw,
                                                unsigned short* __restrict__ bfragkv,
                                                unsigned short* __restrict__ bfragp) {
    const int bx = blockIdx.x;
    const int t = threadIdx.x;
    float v[4];
    if (bx < 2048) {
        // w_q: B[k=i][n=e*128+p], K=1024 (KC=32), N=2048
        const unsigned u = bx * 256 + t;
        const int p = u & 127, e = (u >> 7) & 15, kk = u >> 11;
#pragma unroll
        for (int d = 0; d < 4; ++d) v[d] = w_q[(size_t)e * 131072 + (size_t)(4 * kk + d) * 128 + p];
        const int n = e * 128 + p;
        const int nt = n >> 4, kc = kk >> 3;
        const int lane = ((kk & 7) >> 1) * 16 + (n & 15);
        const size_t off = (((size_t)nt * 32 + kc) * 64 + lane) * 8 + 4 * (kk & 1);
        uint2 o;
        o.x = (unsigned)f2bf(v[0]) | ((unsigned)f2bf(v[1]) << 16);
        o.y = (unsigned)f2bf(v[2]) | ((unsigned)f2bf(v[3]) << 16);
        *(uint2*)(bfragq + off) = o;
    } else if (bx < 4096) {
        // w_out: row-major 2048x1024, K=2048 (KC=64), N=1024
        const unsigned u = (bx - 2048) * 256 + t;
        const int n = ((bx & 3) * 256 + t) & 1023;
        const int kk = u >> 10;
#pragma unroll
        for (int d = 0; d < 4; ++d) v[d] = w_out[(size_t)(4 * kk + d) * 1024 + n];
        const int nt = n >> 4, kc = kk >> 3;
        const int lane = ((kk & 7) >> 1) * 16 + (n & 15);
        const size_t off = (((size_t)nt * 64 + kc) * 64 + lane) * 8 + 4 * (kk & 1);
        uint2 o;
        o.x = (unsigned)f2bf(v[0]) | ((unsigned)f2bf(v[1]) << 16);
        o.y = (unsigned)f2bf(v[2]) | ((unsigned)f2bf(v[3]) << 16);
        *(uint2*)(bfragw + off) = o;
    } else if (bx < 4352) {
        // w_kv: row-major 1024x256, K=1024 (KC=32), N=256
        const int n = t;
        const int kk = bx - 4096;
#pragma unroll
        for (int d = 0; d < 4; ++d) v[d] = w_kv[(size_t)(4 * kk + d) * 256 + n];
        const int nt = n >> 4, kc = kk >> 3;
        const int lane = ((kk & 7) >> 1) * 16 + (n & 15);
        const size_t off = (((size_t)nt * 32 + kc) * 64 + lane) * 8 + 4 * (kk & 1);
        uint2 o;
        o.x = (unsigned)f2bf(v[0]) | ((unsigned)f2bf(v[1]) << 16);
        o.y = (unsigned)f2bf(v[2]) | ((unsigned)f2bf(v[3]) << 16);
        *(uint2*)(bfragkv + off) = o;
    } else {
        // pos_pk: (128,1024) row-major; B[k=d][n=p] = pos_pk[p][d]; K=1024 (KC=32), N=128
        // block n = bx-4352 (one row, coalesced read); thread t covers k=4t..4t+3
        const int n = bx - 4352;
#pragma unroll
        for (int d = 0; d < 4; ++d) v[d] = pos_pk[(size_t)n * 1024 + 4 * t + d];
        const int nt = n >> 4, kc = t >> 3;
        const int lane = ((t & 7) >> 1) * 16 + (n & 15);
        const size_t off = (((size_t)nt * 32 + kc) * 64 + lane) * 8 + 4 * (t & 1);
        uint2 o;
        o.x = (unsigned)f2bf(v[0]) | ((unsigned)f2bf(v[1]) << 16);
        o.y = (unsigned)f2bf(v[2]) | ((unsigned)f2bf(v[3]) << 16);
        *(uint2*)(bfragp + off) = o;
    }
}

// ---------------- Kernel: sinusoidal pos embedding -> A-frag bf16 (2048 x 1024, row 2047 = 0) ----------------
__global__ __launch_bounds__(256) void k_pe(unsigned short* __restrict__ pefrag) {
    const int m = blockIdx.x;          // tp 0..2047
    const int t = threadIdx.x;         // k = 4t..4t+3
    uint2 o;
    if (m >= 2047) {
        o.x = 0u; o.y = 0u;
    } else {
        const float c1 = -logf(10000.f) / 1024.f;
        const float pos = (float)(m - 1023);
        const float a0 = pos * expf((float)(4 * t) * c1);
        const float a1 = pos * expf((float)(4 * t + 2) * c1);
        o.x = (unsigned)f2bf(sinf(a0)) | ((unsigned)f2bf(cosf(a0)) << 16);
        o.y = (unsigned)f2bf(sinf(a1)) | ((unsigned)f2bf(cosf(a1)) << 16);
    }
    const int mt = m >> 4, kc = t >> 3;
    const int lane = ((t & 7) >> 1) * 16 + (m & 15);
    const size_t off = (((size_t)mt * 32 + kc) * 64 + lane) * 8 + 4 * (t & 1);
    *(uint2*)(pefrag + off) = o;
}

// ---------------- MFMA GEMM core: 128x64 tile, 4 waves, frag-ordered global in ----------------
__device__ __forceinline__ void gemm_core64(const unsigned short* __restrict__ Afrag,
                                            const unsigned short* __restrict__ Bfrag,
                                            int mt0, int nt0, int KC,
                                            unsigned short (*aT)[512],
                                            unsigned short (*bT)[512],
                                            floatx4 acc[4][2]) {
    const int t = threadIdx.x;
    const int w = t >> 6, lane = t & 63;
    const int wm = w >> 1, wn = w & 1;
    for (int kc = 0; kc < KC; ++kc) {
        __syncthreads();
        {
            const int fi = w * 3;
#pragma unroll
            for (int l = 0; l < 3; ++l) {
                const int f = fi + l;   // 0..11: 8 A-frags then 4 B-frags
                if (f < 8)
                    gload16(Afrag + (((size_t)(mt0 + f) * KC + kc) * 64 + lane) * 8, &aT[f][0]);
                else
                    gload16(Bfrag + (((size_t)(nt0 + f - 8) * KC + kc) * 64 + lane) * 8, &bT[f - 8][0]);
            }
        }
        __syncthreads();
        short8 af[4], bf[2];
#pragma unroll
        for (int i = 0; i < 4; ++i) af[i] = *(const short8*)&aT[wm * 4 + i][lane * 8];
#pragma unroll
        for (int j = 0; j < 2; ++j) bf[j] = *(const short8*)&bT[wn * 2 + j][lane * 8];
#pragma unroll
        for (int i = 0; i < 4; ++i)
#pragma unroll
            for (int j = 0; j < 2; ++j)
                acc[i][j] = __builtin_amdgcn_mfma_f32_16x16x32_bf16(af[i], bf[j], acc[i][j], 0, 0, 0);
    }
}

// ---------------- GEMM: kpos = pe @ pos_pk^T * sc -> kposfg B-frag layout ----------------
__global__ __launch_bounds__(256) void k_gemm_kpos(const unsigned short* __restrict__ Afrag,
                                                   const unsigned short* __restrict__ Bfrag,
                                                   const float* __restrict__ scale,
                                                   unsigned short* __restrict__ kposfg) {
    __shared__ __align__(16) unsigned short aT[8][512], bT[4][512];
    floatx4 acc[4][2];
#pragma unroll
    for (int i = 0; i < 4; ++i) { acc[i][0] = (floatx4){0,0,0,0}; acc[i][1] = (floatx4){0,0,0,0}; }
    gemm_core64(Afrag, Bfrag, blockIdx.x * 8, blockIdx.y * 4, 32, aT, bT, acc);
    const float sc = sqrtf(scale[0]);
    const int t = threadIdx.x, w = t >> 6, lane = t & 63;
    const int wm = w >> 1, wn = w & 1, lq = lane >> 4, lm = lane & 15;
#pragma unroll
    for (int i = 0; i < 4; ++i)
#pragma unroll
        for (int j = 0; j < 2; ++j) {
            const int p = blockIdx.y * 64 + (wn * 2 + j) * 16 + lm;
#pragma unroll
            for (int r = 0; r < 4; ++r) {
                const int tp = blockIdx.x * 128 + (wm * 4 + i) * 16 + lq * 4 + r;
                const size_t addr = (((size_t)(tp >> 4) * 4 + (p >> 5)) * 64 +
                                     ((p & 31) >> 3) * 16 + (tp & 15)) * 8 + (p & 7);
                kposfg[addr] = f2bf(acc[i][j][r] * sc);
            }
        }
}

// ---------------- GEMM: qall = curr @ [w_q] * sc -> bf16 row-major 4096x2048 ----------------
__global__ __launch_bounds__(256) void k_gemm_qall(const unsigned short* __restrict__ Afrag,
                                                   const unsigned short* __restrict__ Bfrag,
                                                   const float* __restrict__ scale,
                                                   unsigned short* __restrict__ qall) {
    __shared__ __align__(16) unsigned short aT[8][512], bT[4][512];
    floatx4 acc[4][2];
#pragma unroll
    for (int i = 0; i < 4; ++i) { acc[i][0] = (floatx4){0,0,0,0}; acc[i][1] = (floatx4){0,0,0,0}; }
    gemm_core64(Afrag, Bfrag, blockIdx.x * 8, blockIdx.y * 4, 32, aT, bT, acc);
    const float sc = sqrtf(scale[0]);
    const int t = threadIdx.x, w = t >> 6, lane = t & 63;
    const int wm = w >> 1, wn = w & 1, lq = lane >> 4, lm = lane & 15;
#pragma unroll
    for (int i = 0; i < 4; ++i)
#pragma unroll
        for (int j = 0; j < 2; ++j)
#pragma unroll
            for (int r = 0; r < 4; ++r)
                qall[(size_t)(blockIdx.x * 128 + (wm * 4 + i) * 16 + lq * 4 + r) * 2048 +
                     blockIdx.y * 64 + (wn * 2 + j) * 16 + lm] = f2bf(acc[i][j][r] * sc);
}

// ---------------- GEMM: out = zfrag @ w_out -> f32 row-major 4096x1024 ----------------
__global__ __launch_bounds__(256) void k_gemm_out(const unsigned short* __restrict__ Afrag,
                                                  const unsigned short* __restrict__ Bfrag,
                                                  float* __restrict__ out) {
    __shared__ __align__(16) unsigned short aT[8][512], bT[4][512];
    floatx4 acc[4][2];
#pragma unroll
    for (int i = 0; i < 4; ++i) { acc[i][0] = (floatx4){0,0,0,0}; acc[i][1] = (floatx4){0,0,0,0}; }
    gemm_core64(Afrag, Bfrag, blockIdx.x * 8, blockIdx.y * 4, 64, aT, bT, acc);
    const int t = threadIdx.x, w = t >> 6, lane = t & 63;
    const int wm = w >> 1, wn = w & 1, lq = lane >> 4, lm = lane & 15;
#pragma unroll
    for (int i = 0; i < 4; ++i)
#pragma unroll
        for (int j = 0; j < 2; ++j)
#pragma unroll
            for (int r = 0; r < 4; ++r)
                out[(size_t)(blockIdx.x * 128 + (wm * 4 + i) * 16 + lq * 4 + r) * 1024 +
                    blockIdx.y * 64 + (wn * 2 + j) * 16 + lm] = acc[i][j][r];
}

// ---------------- GEMM: kv = attend @ w_kv -> K/V B-fragment layouts (bf16) ----------------
__global__ __launch_bounds__(256) void k_gemm_kv(const unsigned short* __restrict__ Afrag,
                                                 const unsigned short* __restrict__ Bfrag,
                                                 const float* __restrict__ scale,
                                                 unsigned short* __restrict__ kfragg,
                                                 unsigned short* __restrict__ vfragg) {
    __shared__ __align__(16) unsigned short aT[8][512], bT[4][512];
    floatx4 acc[4][2];
#pragma unroll
    for (int i = 0; i < 4; ++i) { acc[i][0] = (floatx4){0,0,0,0}; acc[i][1] = (floatx4){0,0,0,0}; }
    gemm_core64(Afrag, Bfrag, blockIdx.x * 8, blockIdx.y * 4, 32, aT, bT, acc);
    const float sc = sqrtf(scale[0]);
    const int t = threadIdx.x, w = t >> 6, lane = t & 63;
    const int wm = w >> 1, wn = w & 1, lq = lane >> 4, lm = lane & 15;
#pragma unroll
    for (int i = 0; i < 4; ++i)
#pragma unroll
        for (int j = 0; j < 2; ++j) {
            const int n = blockIdx.y * 64 + (wn * 2 + j) * 16 + lm;
#pragma unroll
            for (int r = 0; r < 4; ++r) {
                const int tok = blockIdx.x * 128 + (wm * 4 + i) * 16 + lq * 4 + r;
                const int bb = tok >> 10, jj = tok & 1023;
                if (n < 128) {
                    const int p = n;
                    const size_t addr = ((((size_t)bb * 64 + (jj >> 4)) * 4 + (p >> 5)) * 64 +
                                         ((p & 31) >> 3) * 16 + (jj & 15)) * 8 + (p & 7);
                    kfragg[addr] = f2bf(acc[i][j][r] * sc);
                } else {
                    const int p = n - 128;
                    const size_t addr = ((((size_t)bb * 32 + (jj >> 5)) * 8 + (p >> 4)) * 64 +
                                         ((jj & 31) >> 3) * 16 + (p & 15)) * 8 + (jj & 7);
                    vfragg[addr] = f2bf(acc[i][j][r]);
                }
            }
        }
}

// ---------------- k_attn (unchanged from R6): head-shared blocks, rolling kpos window ----------------
#define ATTN_FM 8.0f

__device__ __forceinline__ void attn_step6(const char*& pk, const char*& pv, const char*& pp,
                                           short8 (&kf)[8], short8 (&kfN)[8],
                                           const short8 (&cry)[4], short8 (&n1)[4], short8 (&n2)[4],
                                           const short8 (&qf)[4], const short8& onesf,
                                           floatx4 (&acc)[8], floatx4& accl,
                                           unsigned short* __restrict__ pl,
                                           const int loff,
                                           const int (&baddr)[4], const int (&bsel)[4],
                                           const int lq, const int lm) {
#pragma unroll
    for (int c = 0; c < 4; ++c) {
        n1[c] = *(const short8*)(pp + 4096 + c * 1024 + loff);
        n2[c] = *(const short8*)(pp + 8192 + c * 1024 + loff);
    }
    short8 vf[8];
#pragma unroll
    for (int nt = 0; nt < 8; ++nt)
        vf[nt] = *(const short8*)(pv + nt * 1024 + loff);
#pragma unroll
    for (int q = 0; q < 8; ++q)
        kfN[q] = *(const short8*)(pk + 8192 + q * 1024 + loff);

    floatx4 sk0 = {0.f, 0.f, 0.f, 0.f}, sk1 = {0.f, 0.f, 0.f, 0.f};
#pragma unroll
    for (int c = 0; c < 4; ++c) {
        sk0 = __builtin_amdgcn_mfma_f32_16x16x32_bf16(qf[c], kf[c], sk0, 0, 0, 0);
        sk1 = __builtin_amdgcn_mfma_f32_16x16x32_bf16(qf[c], kf[4 + c], sk1, 0, 0, 0);
    }
    floatx4 sp0 = {0.f, 0.f, 0.f, 0.f}, sp1 = {0.f, 0.f, 0.f, 0.f}, sp2 = {0.f, 0.f, 0.f, 0.f};
#pragma unroll
    for (int c = 0; c < 4; ++c) {
        sp0 = __builtin_amdgcn_mfma_f32_16x16x32_bf16(qf[c], cry[c], sp0, 0, 0, 0);
        sp1 = __builtin_amdgcn_mfma_f32_16x16x32_bf16(qf[c], n1[c], sp1, 0, 0, 0);
        sp2 = __builtin_amdgcn_mfma_f32_16x16x32_bf16(qf[c], n2[c], sp2, 0, 0, 0);
    }
#pragma unroll
    for (int r = 0; r < 4; ++r) {
        const int a = baddr[r];
        const float b0 = __int_as_float(__builtin_amdgcn_ds_bpermute(a, __float_as_int(sp0[r])));
        const float b1 = __int_as_float(__builtin_amdgcn_ds_bpermute(a, __float_as_int(sp1[r])));
        const float b2 = __int_as_float(__builtin_amdgcn_ds_bpermute(a, __float_as_int(sp2[r])));
        const float v0 = sk0[r] + (bsel[r] ? b0 : b1);
        const float v1 = sk1[r] + (bsel[r] ? b1 : b2);
        pl[(lq * 4 + r) * 56 + lm]      = f2bf(__expf(v0 - ATTN_FM));
        pl[(lq * 4 + r) * 56 + 16 + lm] = f2bf(__expf(v1 - ATTN_FM));
    }
    asm volatile("" ::: "memory");
    const short8 pf = *(const short8*)(pl + lm * 56 + lq * 8);
#pragma unroll
    for (int nt = 0; nt < 8; ++nt)
        acc[nt] = __builtin_amdgcn_mfma_f32_16x16x32_bf16(pf, vf[nt], acc[nt], 0, 0, 0);
    accl = __builtin_amdgcn_mfma_f32_16x16x32_bf16(pf, onesf, accl, 0, 0, 0);
    pk += 8192; pv += 8192; pp += 8192;
}

__global__ __launch_bounds__(256, 2) void k_attn(const unsigned short* __restrict__ qall,
                                                 const unsigned short* __restrict__ kfragg,
                                                 const unsigned short* __restrict__ vfragg,
                                                 const unsigned short* __restrict__ kposfg,
                                                 const int* __restrict__ selidx,
                                                 const float* __restrict__ selval,
                                                 unsigned short* __restrict__ zfrag) {
    __shared__ __align__(16) unsigned short plds[2][4][16][56];  // 14 KB

    const int t = threadIdx.x;
    const int w = t >> 6, lane = t & 63;
    const int st = blockIdx.x & 63;
    const int hg = (blockIdx.x >> 6) & 1;
    const int b = blockIdx.x >> 7;
    const int h = hg * 4 + w;
    const int s0 = st * 16;
    const int lq = lane >> 4;
    const int lm = lane & 15;
    const int loff = lane * 16;

    short8 qf[4];
    {
        const int token = b * 1024 + s0 + lm;
        const int e = selidx[token * 8 + h];
        const unsigned short* qb = qall + (size_t)token * 2048 + e * 128 + lq * 8;
#pragma unroll
        for (int c = 0; c < 4; ++c) qf[c] = *(const short8*)(qb + c * 32);
    }
    short8 onesf;
#pragma unroll
    for (int i = 0; i < 8; ++i) onesf[i] = (short)0x3F80;

    int baddr[4], bsel[4];
#pragma unroll
    for (int r = 0; r < 4; ++r) {
        const int c0 = 15 + lm - (lq * 4 + r);
        baddr[r] = (lq * 16 + (c0 & 15)) * 4;
        bsel[r] = (c0 < 16) ? 1 : 0;
    }

    floatx4 acc[8], accl;
#pragma unroll
    for (int nt = 0; nt < 8; ++nt) acc[nt] = (floatx4){0.f, 0.f, 0.f, 0.f};
    accl = (floatx4){0.f, 0.f, 0.f, 0.f};

    const char* pk = (const char*)kfragg + (size_t)b * 262144;
    const char* pv = (const char*)vfragg + (size_t)b * 262144;
    const char* pp = (const char*)kposfg + (size_t)((1008 - s0) >> 4) * 4096;

    short8 kfA[8], kfB[8];
#pragma unroll
    for (int q = 0; q < 8; ++q)
        kfA[q] = *(const short8*)(pk + q * 1024 + loff);
    short8 cry[4], n1a[4], n2a[4], n1b[4], n2b[4];
#pragma unroll
    for (int c = 0; c < 4; ++c)
        cry[c] = *(const short8*)(pp + c * 1024 + loff);

    unsigned short* pl0 = &plds[0][w][0][0];
    unsigned short* pl1 = &plds[1][w][0][0];
    for (int it2 = 0; it2 < 16; ++it2) {
        attn_step6(pk, pv, pp, kfA, kfB, cry, n1a, n2a, qf, onesf, acc, accl, pl0, loff, baddr, bsel, lq, lm);
        attn_step6(pk, pv, pp, kfB, kfA, n2a, n1b, n2b, qf, onesf, acc, accl, pl1, loff, baddr, bsel, lq, lm);
#pragma unroll
        for (int c = 0; c < 4; ++c) cry[c] = n2b[c];
    }

#pragma unroll
    for (int r = 0; r < 4; ++r) {
        const int tok = b * 1024 + s0 + lq * 4 + r;
        const int e = selidx[tok * 8 + h];
        const float g = selval[tok * 8 + h] / accl[r];
        const int mt = tok >> 4, tm = tok & 15;
#pragma unroll
        for (int nt = 0; nt < 8; ++nt) {
            const int k = e * 128 + nt * 16 + lm;
            const int kc = k >> 5;
            const int lane2 = (((k & 31) >> 3) << 4) + tm;
            zfrag[(((size_t)mt * 64 + kc) * 64 + lane2) * 8 + (k & 7)] = f2bf(acc[nt][r] * g);
        }
    }
}

extern "C" void kernel_launch(void* const* d_in, const int* in_sizes, int n_in,
                              void* d_out, int out_size, void* d_ws, size_t ws_size,
                              hipStream_t stream) {
    const float* curr    = (const float*)d_in[0];  // (4,1024,1024)
    const float* attend  = (const float*)d_in[1];  // (4,1024,1024)
    const float* w_q     = (const float*)d_in[2];  // (16,1024,128)
    const float* w_kv    = (const float*)d_in[3];  // (1024,256)
    const float* w_out   = (const float*)d_in[4];  // (16,128,1024)
    const float* pos_pk  = (const float*)d_in[5];  // (128,1024)
    const float* sel_dst = (const float*)d_in[6];  // (16,1024)
    const float* scale   = (const float*)d_in[7];  // (1,)
    float* out = (float*)d_out;

    char* ws = (char*)d_ws;
    float* selval = (float*)ws;                                        // 128 KB
    int*   selidx = (int*)(ws + 131072);                               // 128 KB
    unsigned short* kposfg  = (unsigned short*)(ws + 262144);          // 512 KB
    unsigned short* kfragg  = (unsigned short*)(ws + 786432);          // 1 MB
    unsigned short* vfragg  = (unsigned short*)(ws + 1835008);         // 1 MB
    unsigned short* bfragq  = (unsigned short*)(ws + 2883584);         // 4 MB
    unsigned short* bfragw  = (unsigned short*)(ws + 7077888);         // 4 MB
    unsigned short* bfragkv = (unsigned short*)(ws + 11272192);        // 512 KB
    unsigned short* afrag   = (unsigned short*)(ws + 11796480);        // 8 MB (curr, then attend)
    unsigned short* qall    = (unsigned short*)(ws + 20185088);        // 16 MB
    unsigned short* zfrag   = (unsigned short*)(ws + 36962304);        // 16 MB
    // pe A-frag (4 MB) and pos_pk B-frag (256 KB) alias the front of zfrag:
    // both are fully consumed by k_gemm_kpos BEFORE zfrag's memset.
    unsigned short* pefrag  = zfrag;                                   // 4 MB
    unsigned short* bfragp  = zfrag + 2097152;                         // 256 KB
    // total ~51.3 MB

    k_conv_w<<<4480, 256, 0, stream>>>(w_q, w_out, w_kv, pos_pk, bfragq, bfragw, bfragkv, bfragp);
    k_sel<<<4096, 256, 0, stream>>>(curr, sel_dst, selval, selidx, afrag);
    k_pe<<<2048, 256, 0, stream>>>(pefrag);
    k_gemm_kpos<<<dim3(16, 2), 256, 0, stream>>>(pefrag, bfragp, scale, kposfg);
    k_gemm_qall<<<dim3(32, 32), 256, 0, stream>>>(afrag, bfragq, scale, qall);
    k_conv_act<<<4096, 256, 0, stream>>>(attend, afrag);               // reuse afrag
    k_gemm_kv<<<dim3(32, 4), 256, 0, stream>>>(afrag, bfragkv, scale, kfragg, vfragg);
    hipMemsetAsync(zfrag, 0, (size_t)16777216, stream);
    k_attn<<<512, 256, 0, stream>>>(qall, kfragg, vfragg, kposfg, selidx, selval, zfrag);
    k_gemm_out<<<dim3(32, 16), 256, 0, stream>>>(zfrag, bfragw, out);
}